// Round 7
// baseline (243.980 us; speedup 1.0000x reference)
//
#include <hip/hip_runtime.h>
#include <math.h>

// Capsule routing B=32, N=1024(j), D=256(k), NC=32(i), DC=64(d). Factored
// (no u_hat), MFMA 16x16x32 bf16 with hi/lo splits where it matters:
//   delta[j,i] = U[b,j,:].w[:,i]   (Uhi x (w hi+lo) MFMA)
//   e = exp(logit), sef = sum_j e  (fp32)
//   t^T[k,i] += Ut[k,j].e^T[j,i]   (Uhi x (e hi+lo) MFMA; U-lo dropped: ~0.2% on v)
//   s = tW_i; v = s*rsqrt(||s||^2+eps*sef^2); w = W_i v  (fp32, fused in-block)
// 4 launches: colsum -> pass0 (sv+routing) -> pass1 (sv+routing) -> final sv.
// tpart/sefpart double-buffered (no cross-block race inside pass1).

typedef short v8s __attribute__((ext_vector_type(8)));
typedef short v4s __attribute__((ext_vector_type(4)));
typedef short v2s __attribute__((ext_vector_type(2)));
typedef float v4f __attribute__((ext_vector_type(4)));

__device__ __forceinline__ unsigned short f2bf(float x) {
    unsigned u = __float_as_uint(x);
    u = u + 0x7fffu + ((u >> 16) & 1u);
    return (unsigned short)(u >> 16);
}
__device__ __forceinline__ float bf2f(unsigned short h) {
    return __uint_as_float(((unsigned)h) << 16);
}

// ---------------------------------------------------------------------------
// colsum partials, iteration-0 uniform c: t0p[b][q][k] = mean over 64 j rows
__global__ __launch_bounds__(256) void k_colsum(const float* __restrict__ U,
                                                float* __restrict__ t0p) {
    int b = blockIdx.x, q = blockIdx.y, k = threadIdx.x;
    const float* Up = U + (((b << 10) + (q << 6)) << 8) + k;
    float acc = 0.f;
    #pragma unroll 16
    for (int jl = 0; jl < 64; ++jl) acc += Up[jl << 8];
    t0p[(b << 12) + (q << 8) + k] = acc * (1.0f / 1024.0f);
}

// ---------------------------------------------------------------------------
// sv for a 16-capsule group (1024 threads): s-phase thread=(i=tid>>6,d=tid&63),
// wave == capsule -> in-wave norm reduce; w-phase thread=(i,k4) writes bf16
// hi/lo w into LDS for the MFMA. t_lds: [16][256] (tstr=256) or [256] (tstr=0).
__device__ __forceinline__ void sv16(const float* __restrict__ W,
                                     const float* t_lds, int tstr,
                                     const float* sefv_lds, int usesef,
                                     float* v_lds, short* s_wh, short* s_wl,
                                     float* outp, int icap0, int tid, int doW) {
    int i = tid >> 6, d = tid & 63;
    {
        const float* Wc = W + ((icap0 + i) << 6) + d;
        const float4* t4 = (const float4*)(t_lds + i * tstr);
        float s = 0.f;
        #pragma unroll 8
        for (int k4 = 0; k4 < 64; ++k4) {
            float4 tv = t4[k4];
            const float* wp = Wc + (k4 << 2) * 2048;
            s += tv.x * wp[0] + tv.y * wp[2048] + tv.z * wp[4096] + tv.w * wp[6144];
        }
        float n2 = s * s;
        #pragma unroll
        for (int m = 1; m < 64; m <<= 1) n2 += __shfl_xor(n2, m, 64);
        float sf = usesef ? sefv_lds[i] : 1.0f;
        float v = s * rsqrtf(n2 + 1e-7f * sf * sf);
        v_lds[tid] = v;                                // [i][d]
        if (outp) outp[((icap0 + i) << 6) + d] = v;
    }
    if (!doW) return;
    // w-phase: same wave handles same i -> v_lds write->read is wave-local (safe)
    {
        int k4 = tid & 63;
        const float4* v4 = (const float4*)(v_lds + (i << 6));
        float w[4] = {0.f, 0.f, 0.f, 0.f};
        float4 vr[8];
        #pragma unroll
        for (int q = 0; q < 8; ++q) vr[q] = v4[q];
        #pragma unroll
        for (int kk = 0; kk < 4; ++kk) {
            const float4* Wr = (const float4*)(W + ((k4 << 2) + kk) * 2048 + ((icap0 + i) << 6));
            #pragma unroll
            for (int q = 0; q < 8; ++q) {
                float4 a = Wr[q];
                w[kk] += a.x * vr[q].x + a.y * vr[q].y + a.z * vr[q].z + a.w * vr[q].w;
            }
        }
        #pragma unroll
        for (int q = 0; q < 8; ++q) vr[q] = v4[q + 8];
        #pragma unroll
        for (int kk = 0; kk < 4; ++kk) {
            const float4* Wr = (const float4*)(W + ((k4 << 2) + kk) * 2048 + ((icap0 + i) << 6));
            #pragma unroll
            for (int q = 0; q < 8; ++q) {
                float4 a = Wr[q + 8];
                w[kk] += a.x * vr[q].x + a.y * vr[q].y + a.z * vr[q].z + a.w * vr[q].w;
            }
        }
        unsigned short wh[4], wl[4];
        #pragma unroll
        for (int kk = 0; kk < 4; ++kk) {
            wh[kk] = f2bf(w[kk]);
            wl[kk] = f2bf(w[kk] - bf2f(wh[kk]));
        }
        *(v4s*)&s_wh[i * 264 + (k4 << 2)] =
            (v4s){(short)wh[0], (short)wh[1], (short)wh[2], (short)wh[3]};
        *(v4s*)&s_wl[i * 264 + (k4 << 2)] =
            (v4s){(short)wl[0], (short)wl[1], (short)wl[2], (short)wl[3]};
    }
}

// ---------------------------------------------------------------------------
// stage a (2 j-rows, 4 k) group: U-hi row-major (delta A) + U-hi transposed (t A)
__device__ __forceinline__ void stage_write(short* Uh, short* Th, int j0, int k0,
                                            const float4& g0, const float4& g1) {
    float a0[4] = {g0.x, g0.y, g0.z, g0.w};
    float a1[4] = {g1.x, g1.y, g1.z, g1.w};
    unsigned short h0[4], h1[4];
    #pragma unroll
    for (int e = 0; e < 4; ++e) { h0[e] = f2bf(a0[e]); h1[e] = f2bf(a1[e]); }
    *(v4s*)&Uh[j0 * 264 + k0] =
        (v4s){(short)h0[0], (short)h0[1], (short)h0[2], (short)h0[3]};
    *(v4s*)&Uh[(j0 + 1) * 264 + k0] =
        (v4s){(short)h1[0], (short)h1[1], (short)h1[2], (short)h1[3]};
    #pragma unroll
    for (int e = 0; e < 4; ++e)
        *(v2s*)&Th[(k0 + e) * 40 + j0] = (v2s){(short)h0[e], (short)h1[e]};
}

// ---------------------------------------------------------------------------
// fused pass: sv (w from t-partials) then routing over this block's 256-j slice.
// grid 256: b = blk&31 (same-b blocks share XCD), p = (blk>>6)&3... see decode.
__global__ __launch_bounds__(1024) void k_pass(const float* __restrict__ U,
                                               const float* __restrict__ W,
                                               const float* __restrict__ t0p,
                                               const float* __restrict__ tpart_in,
                                               const float* __restrict__ sefpart_in,
                                               float* __restrict__ bmatg,
                                               float* __restrict__ tpart_out,
                                               float* __restrict__ sefpart_out,
                                               int addold) {
    __shared__ short s_Uh[2][32 * 264];              // 33.8 KB
    __shared__ short s_Th[2][256 * 40];              // 41 KB
    __shared__ short s_wh[16 * 264];                 // 8.4 KB
    __shared__ short s_wl[16 * 264];                 // 8.4 KB
    __shared__ short s_eh[16 * 40];
    __shared__ short s_el[16 * 40];
    __shared__ __align__(16) float t_lds[16 * 256];  // 16 KB
    __shared__ float v_lds[1024];
    __shared__ float sefv[16];

    const int tid = threadIdx.x;
    const int wv = tid >> 6, lane = tid & 63;
    const int quad = lane >> 4, nn = lane & 15;
    const int blk = blockIdx.x;
    const int b = blk & 31, pg = blk >> 5;
    const int p = pg >> 1, g2 = pg & 1;
    const int bg = (b << 1) | g2;
    const int rowbase = (b << 10) + (p << 8);
    const float4* U4 = (const float4*)U;

    // build t (and sef) for the sv
    if (!addold) {
        if (tid < 256) {
            float a = 0.f;
            const float* tb = t0p + (b << 12) + tid;
            #pragma unroll
            for (int q = 0; q < 16; ++q) a += tb[q << 8];
            t_lds[tid] = a;
        }
    } else {
        const float* tb = tpart_in + (bg << 12);
        for (int idx = tid; idx < 4096; idx += 1024)
            t_lds[idx] = tb[idx] + tb[262144 + idx] + tb[524288 + idx] + tb[786432 + idx];
        if (tid < 16) {
            float ssum = 0.f;
            #pragma unroll
            for (int q = 0; q < 8; ++q)
                ssum += sefpart_in[(q << 10) + (bg << 4) + tid];
            sefv[tid] = ssum;
        }
    }
    __syncthreads();
    sv16(W, t_lds, addold ? 256 : 0, sefv, addold, v_lds, s_wh, s_wl,
         nullptr, g2 << 4, tid, 1);
    // prologue: stage tile 0
    {
        int j0 = wv << 1;
        float4 g0 = U4[(rowbase + j0) * 64 + lane];
        float4 g1 = U4[(rowbase + j0 + 1) * 64 + lane];
        stage_write(s_Uh[0], s_Th[0], j0, lane << 2, g0, g1);
    }
    __syncthreads();

    v4f acc = {0.f, 0.f, 0.f, 0.f};
    float sefacc = 0.f;
    const int jg0 = p << 8;

    for (int t = 0; t < 8; ++t) {
        const int cur = t & 1;
        float4 g0, g1;
        if (t < 7) {
            int j0 = wv << 1;
            int r = (rowbase + ((t + 1) << 5) + j0) * 64 + lane;
            g0 = U4[r];
            g1 = U4[r + 64];
        }
        if (wv < 2) {
            float bold[4];
            if (addold) {
                #pragma unroll
                for (int r = 0; r < 4; ++r) {
                    int j_loc = (wv << 4) + (quad << 2) + r;
                    bold[r] = bmatg[(((b << 5) + (g2 << 4) + nn) << 10) +
                                    jg0 + (t << 5) + j_loc];
                }
            }
            const short* uhb = &s_Uh[cur][((wv << 4) + nn) * 264 + (quad << 3)];
            const short* whb = &s_wh[nn * 264 + (quad << 3)];
            const short* wlb = &s_wl[nn * 264 + (quad << 3)];
            v4f d1 = {0.f, 0.f, 0.f, 0.f}, d2 = {0.f, 0.f, 0.f, 0.f};
            #pragma unroll
            for (int ks = 0; ks < 8; ++ks) {
                v8s a  = *(const v8s*)(uhb + (ks << 5));
                v8s bh = *(const v8s*)(whb + (ks << 5));
                v8s bl = *(const v8s*)(wlb + (ks << 5));
                d1 = __builtin_amdgcn_mfma_f32_16x16x32_bf16(a, bh, d1, 0, 0, 0);
                d2 = __builtin_amdgcn_mfma_f32_16x16x32_bf16(a, bl, d2, 0, 0, 0);
            }
            #pragma unroll
            for (int r = 0; r < 4; ++r) {
                int j_loc = (wv << 4) + (quad << 2) + r;
                float logit = d1[r] + d2[r];
                if (addold) logit += bold[r];
                else bmatg[(((b << 5) + (g2 << 4) + nn) << 10) + jg0 + (t << 5) + j_loc] = logit;
                float e = __expf(logit);
                sefacc += e;
                unsigned short eh = f2bf(e);
                s_eh[nn * 40 + j_loc] = (short)eh;
                s_el[nn * 40 + j_loc] = (short)f2bf(e - bf2f(eh));
            }
        }
        if (t < 7) {
            int j0 = wv << 1;
            stage_write(s_Uh[cur ^ 1], s_Th[cur ^ 1], j0, lane << 2, g0, g1);
        }
        __syncthreads();   // e(t) + staged(t+1) visible
        {
            v8s ah  = *(const v8s*)&s_Th[cur][((wv << 4) + nn) * 40 + (quad << 3)];
            v8s beh = *(const v8s*)&s_eh[nn * 40 + (quad << 3)];
            v8s bel = *(const v8s*)&s_el[nn * 40 + (quad << 3)];
            acc = __builtin_amdgcn_mfma_f32_16x16x32_bf16(ah, beh, acc, 0, 0, 0);
            acc = __builtin_amdgcn_mfma_f32_16x16x32_bf16(ah, bel, acc, 0, 0, 0);
        }
        __syncthreads();   // t-MFMA reads done before next tile's writes
    }

    // tpart[p][bg][i=nn][k], k = row (quad*4+r) of wave's 16-k M-tile
    #pragma unroll
    for (int r = 0; r < 4; ++r) {
        int k = (wv << 4) + (quad << 2) + r;
        tpart_out[(p << 18) + (bg << 12) + (nn << 8) + k] = acc[r];
    }
    if (wv < 2) {
        float se = sefacc;
        se += __shfl_xor(se, 16, 64);
        se += __shfl_xor(se, 32, 64);
        if (lane < 16)
            sefpart_out[(((p << 1) + wv) << 10) + (bg << 4) + lane] = se;
    }
}

// ---------------------------------------------------------------------------
// final sv -> out. grid 64 (bg), block 1024.
__global__ __launch_bounds__(1024) void k_final(const float* __restrict__ W,
                                                const float* __restrict__ tpart_in,
                                                const float* __restrict__ sefpart_in,
                                                float* __restrict__ out) {
    __shared__ __align__(16) float t_lds[16 * 256];
    __shared__ float v_lds[1024];
    __shared__ float sefv[16];
    const int tid = threadIdx.x;
    const int bg = blockIdx.x;
    const int b = bg >> 1, g2 = bg & 1;
    const float* tb = tpart_in + (bg << 12);
    for (int idx = tid; idx < 4096; idx += 1024)
        t_lds[idx] = tb[idx] + tb[262144 + idx] + tb[524288 + idx] + tb[786432 + idx];
    if (tid < 16) {
        float ssum = 0.f;
        #pragma unroll
        for (int q = 0; q < 8; ++q)
            ssum += sefpart_in[(q << 10) + (bg << 4) + tid];
        sefv[tid] = ssum;
    }
    __syncthreads();
    sv16(W, t_lds, 256, sefv, 1, v_lds, nullptr, nullptr,
         out + ((b << 5) << 6), g2 << 4, tid, 0);
}

// ---------------------------------------------------------------------------
extern "C" void kernel_launch(void* const* d_in, const int* in_sizes, int n_in,
                              void* d_out, int out_size, void* d_ws, size_t ws_size,
                              hipStream_t stream) {
    const float* U = (const float*)d_in[0];   // [32,1024,256]
    const float* W = (const float*)d_in[1];   // [256,2048]
    float* out = (float*)d_out;               // [32,32,64]
    float* ws = (float*)d_ws;

    // ws (floats): total 3,293,184 = 13.2 MB
    float* t0p   = ws;                 // [32][16][256]     = 131,072
    float* bmatg = t0p + 131072;       // [32][32][1024]    = 1,048,576
    float* tpA   = bmatg + 1048576;    // [4][64][16][256]  = 1,048,576
    float* tpB   = tpA + 1048576;      // [4][64][16][256]  = 1,048,576
    float* sefA  = tpB + 1048576;      // [8][64][16]       = 8,192
    float* sefB  = sefA + 8192;        // [8][64][16]       = 8,192

    k_colsum<<<dim3(32, 16), 256, 0, stream>>>(U, t0p);
    k_pass<<<256, 1024, 0, stream>>>(U, W, t0p, nullptr, nullptr,
                                     bmatg, tpA, sefA, 0);
    k_pass<<<256, 1024, 0, stream>>>(U, W, t0p, tpA, sefA,
                                     bmatg, tpB, sefB, 1);
    k_final<<<64, 1024, 0, stream>>>(W, tpB, sefB, out);
}

// Round 8
// 141.690 us; speedup vs baseline: 1.7219x; 1.7219x over previous
//
#include <hip/hip_runtime.h>
#include <math.h>

// Capsule routing B=32, N=1024(j), D=256(k), NC=32(i), DC=64(d). Factored
// (no u_hat), MFMA 16x16x32 bf16:
//   delta[j,i] = U[b,j,:].w[:,i]     (k_pass phase D, Uhi x (w hi+lo))
//   e = exp(logit), sef = sum_j e    (fp32, on MFMA C-frags, all waves)
//   t^T[k,i] += Ut[k,j].e^T[j,i]     (k_pass phase T, Uhi x (e hi+lo))
//   s = tW_i; v = s*rsqrt(||s||^2+eps*sef^2); w = W_i v   (k_sv, fp32)
// Round-8 fixes: all-wave delta (8 waves x 16j), 47 KB LDS -> 2 blocks/CU
// at grid 512, W^T precompute so k_sv w-phase is coalesced, bmat in [bg][j][i]
// layout (4-segment access). 6 plain launches, no atomics, no grid.sync.

typedef short v8s __attribute__((ext_vector_type(8)));
typedef short v4s __attribute__((ext_vector_type(4)));
typedef short v2s __attribute__((ext_vector_type(2)));
typedef float v4f __attribute__((ext_vector_type(4)));

__device__ __forceinline__ unsigned short f2bf(float x) {
    unsigned u = __float_as_uint(x);
    u = u + 0x7fffu + ((u >> 16) & 1u);
    return (unsigned short)(u >> 16);
}
__device__ __forceinline__ float bf2f(unsigned short h) {
    return __uint_as_float(((unsigned)h) << 16);
}

// ---------------------------------------------------------------------------
// k_init: bid<512: colsum partials t0p[b][q][k] (iter-0 uniform softmax);
//         bid>=512: transpose W (256x2048) -> WT (2048x256), 64x64 tiles.
__global__ __launch_bounds__(256) void k_init(const float* __restrict__ U,
                                              const float* __restrict__ W,
                                              float* __restrict__ t0p,
                                              float* __restrict__ WT) {
    int bid = blockIdx.x, tid = threadIdx.x;
    if (bid < 512) {
        int b = bid >> 4, q = bid & 15;
        const float* Up = U + (((b << 10) + (q << 6)) << 8) + tid;
        float acc = 0.f;
        #pragma unroll 16
        for (int jl = 0; jl < 64; ++jl) acc += Up[jl << 8];
        t0p[(b << 12) + (q << 8) + tid] = acc * (1.0f / 1024.0f);
    } else {
        __shared__ float tile[64 * 65];
        int tix = bid - 512;                 // 0..127
        int k0 = (tix >> 5) << 6, c0 = (tix & 31) << 6;
        int cc = tid & 63, g4 = tid >> 6;
        #pragma unroll
        for (int r = 0; r < 16; ++r) {
            int kk = (g4 << 4) + r;
            tile[kk * 65 + cc] = W[(k0 + kk) * 2048 + c0 + cc];
        }
        __syncthreads();
        int kk = tid & 63;
        #pragma unroll
        for (int r = 0; r < 16; ++r) {
            int c = (g4 << 4) + r;
            WT[(c0 + c) * 256 + k0 + kk] = tile[kk * 65 + c];
        }
    }
}

// ---------------------------------------------------------------------------
// k_sv: per (b,iG): t[k] = sum of partials; s = tW_i; v = squash(.,sef);
// w = W_i v -> wbt hi/lo (bf16). grid 1024, block 256.
__global__ __launch_bounds__(256) void k_sv(const float* __restrict__ t0p,
                                            const float* __restrict__ tpart,
                                            const float* __restrict__ sefpart,
                                            const float* __restrict__ W,
                                            const float* __restrict__ WT,
                                            short* __restrict__ wbt_h,
                                            short* __restrict__ wbt_l,
                                            float* __restrict__ out,
                                            int mode, int writeOut) {
    __shared__ float t_lds[256];
    __shared__ float spart[256];
    __shared__ __align__(16) float v_lds[64];
    __shared__ __align__(16) v4f spartw[256];
    __shared__ float sefv_s;
    int bid = blockIdx.x, tid = threadIdx.x;
    int b = bid >> 5, iG = bid & 31;
    int bg = (b << 1) | (iG >> 4), il = iG & 15;

    float acc = 0.f;
    if (mode == 0) {
        const float* tb = t0p + (b << 12) + tid;
        #pragma unroll
        for (int q = 0; q < 16; ++q) acc += tb[q << 8];
        if (tid == 0) sefv_s = 1.0f;
    } else {
        const float* tb = tpart + ((((bg << 4) + il)) << 8) + tid;
        #pragma unroll
        for (int p = 0; p < 8; ++p) acc += tb[p << 18];  // stride 64*16*256
        if (tid == 0) {
            float s = 0.f;
            #pragma unroll
            for (int p = 0; p < 8; ++p) s += sefpart[(((p << 6) + bg) << 4) + il];
            sefv_s = s;
        }
    }
    t_lds[tid] = acc;
    __syncthreads();

    // s-phase: (d = tid&63, kq = tid>>6), coalesced 256B W reads
    int d = tid & 63, kq = tid >> 6;
    const float* Wc = W + ((kq << 6) * 2048) + (iG << 6) + d;
    float s = 0.f;
    #pragma unroll 4
    for (int kk = 0; kk < 64; ++kk)
        s += t_lds[(kq << 6) + kk] * Wc[kk * 2048];
    spart[tid] = s;
    __syncthreads();

    if (tid < 64) {
        float sv = spart[tid] + spart[tid + 64] + spart[tid + 128] + spart[tid + 192];
        float n2 = sv * sv;
        #pragma unroll
        for (int m = 1; m < 64; m <<= 1) n2 += __shfl_xor(n2, m, 64);
        float sf = sefv_s;
        float v = sv * rsqrtf(n2 + 1e-7f * sf * sf);
        v_lds[tid] = v;
        if (writeOut) out[(bid << 6) + tid] = v;
    }
    __syncthreads();
    if (writeOut) return;

    // w-phase: (k4 = tid&63, dq = tid>>6), WT gives coalesced 1KB/instr reads
    int k4 = tid & 63, dq = tid >> 6;
    const float4* WT4 = (const float4*)WT;
    v4f wp = {0.f, 0.f, 0.f, 0.f};
    #pragma unroll
    for (int dd = 0; dd < 16; ++dd) {
        float vv = v_lds[(dq << 4) + dd];
        float4 wt = WT4[((iG << 6) + (dq << 4) + dd) * 64 + k4];
        wp.x += vv * wt.x; wp.y += vv * wt.y; wp.z += vv * wt.z; wp.w += vv * wt.w;
    }
    spartw[(dq << 6) + k4] = wp;
    __syncthreads();
    if (tid < 64) {
        v4f w = spartw[tid] + spartw[64 + tid] + spartw[128 + tid] + spartw[192 + tid];
        float wv4[4] = {w.x, w.y, w.z, w.w};
        unsigned short wh[4], wl[4];
        #pragma unroll
        for (int e = 0; e < 4; ++e) {
            wh[e] = f2bf(wv4[e]);
            wl[e] = f2bf(wv4[e] - bf2f(wh[e]));
        }
        int base = (((bg << 4) + il) << 8) + (tid << 2);
        *(v4s*)&wbt_h[base] = (v4s){(short)wh[0], (short)wh[1], (short)wh[2], (short)wh[3]};
        *(v4s*)&wbt_l[base] = (v4s){(short)wl[0], (short)wl[1], (short)wl[2], (short)wl[3]};
    }
}

// ---------------------------------------------------------------------------
// k_pass: block = (b, p = 128-j slice, g2 = 16-capsule group). grid 512x1024.
// Phase D: 8 waves x 16j M-tiles, K=256 in 8 staged 32k chunks (all threads
// stage). Exp + e hi/lo on C-frags. Phase T: 16 waves x 16k M-tiles, K=128j
// in 4 staged chunks (U^T layout). 47 KB LDS -> 2 blocks/CU.
__global__ __launch_bounds__(1024, 8) void k_pass(const float* __restrict__ U,
                                                  const short* __restrict__ wbt_h,
                                                  const short* __restrict__ wbt_l,
                                                  float* __restrict__ bmatg,
                                                  float* __restrict__ tpart_out,
                                                  float* __restrict__ sefpart_out,
                                                  int addold) {
    __shared__ short s_stage[256 * 40];      // 20 KB; D uses [128j][32k] (8 KB)
    __shared__ short s_wh[16 * 264];         // 8.4 KB
    __shared__ short s_wl[16 * 264];
    __shared__ short s_eh[16 * 136];         // 4.3 KB
    __shared__ short s_el[16 * 136];
    __shared__ float s_sefp[8 * 16];

    const int tid = threadIdx.x, wv = tid >> 6, lane = tid & 63;
    const int quad = lane >> 4, nn = lane & 15;
    const int blk = blockIdx.x;
    const int b = blk & 31, pg = blk >> 5;   // same-b blocks share XCD
    const int p = pg >> 1, g2 = pg & 1;
    const int bg = (b << 1) | g2;
    const int rowbase = (b << 10) + (p << 7);
    const float4* U4 = (const float4*)U;

    // stage w hi/lo
    if (tid < 512) {
        int row = tid >> 5, seg = tid & 31;
        int gidx = (((bg << 4) + row) << 8) + (seg << 3);
        *(v8s*)&s_wh[row * 264 + (seg << 3)] = *(const v8s*)(wbt_h + gidx);
        *(v8s*)&s_wl[row * 264 + (seg << 3)] = *(const v8s*)(wbt_l + gidx);
    }

    // ---- phase D ----
    v4f dacc = {0.f, 0.f, 0.f, 0.f};
    const int jr = tid >> 3, ko = tid & 7;   // staging map: 128j x 8 f4
    for (int kc = 0; kc < 8; ++kc) {
        __syncthreads();
        {
            float4 g = U4[(rowbase + jr) * 64 + (kc << 3) + ko];
            *(v4s*)&s_stage[jr * 32 + (ko << 2)] =
                (v4s){(short)f2bf(g.x), (short)f2bf(g.y),
                      (short)f2bf(g.z), (short)f2bf(g.w)};
        }
        __syncthreads();
        if (wv < 8) {
            v8s a  = *(const v8s*)&s_stage[((wv << 4) + nn) * 32 + (quad << 3)];
            v8s bh = *(const v8s*)&s_wh[nn * 264 + (kc << 5) + (quad << 3)];
            v8s bl = *(const v8s*)&s_wl[nn * 264 + (kc << 5) + (quad << 3)];
            dacc = __builtin_amdgcn_mfma_f32_16x16x32_bf16(a, bh, dacc, 0, 0, 0);
            dacc = __builtin_amdgcn_mfma_f32_16x16x32_bf16(a, bl, dacc, 0, 0, 0);
        }
    }
    // epilogue: logits -> exp -> e hi/lo + sef partials (8 waves, parallel)
    if (wv < 8) {
        float sefl = 0.f;
        #pragma unroll
        for (int r = 0; r < 4; ++r) {
            int jloc = (wv << 4) + (quad << 2) + r;
            int ga = (((bg << 10) + (p << 7) + jloc) << 4) + nn;  // [bg][j][i]
            float logit = dacc[r];
            if (addold) logit += bmatg[ga];
            else bmatg[ga] = logit;
            float e = __expf(logit);
            sefl += e;
            unsigned short eh = f2bf(e);
            s_eh[nn * 136 + jloc] = (short)eh;
            s_el[nn * 136 + jloc] = (short)f2bf(e - bf2f(eh));
        }
        float se = sefl;
        se += __shfl_xor(se, 16, 64);
        se += __shfl_xor(se, 32, 64);
        if (lane < 16) s_sefp[(wv << 4) + lane] = se;
    }

    // ---- phase T ----
    v4f tacc = {0.f, 0.f, 0.f, 0.f};
    const int j0 = wv << 1;                  // staging: 2 j-rows x 64 f4 lanes
    for (int jc = 0; jc < 4; ++jc) {
        __syncthreads();                     // e/stage writers done; prev reads done
        {
            int r0 = (rowbase + (jc << 5) + j0) * 64 + lane;
            float4 g0 = U4[r0], g1 = U4[r0 + 64];
            float a0[4] = {g0.x, g0.y, g0.z, g0.w};
            float a1[4] = {g1.x, g1.y, g1.z, g1.w};
            #pragma unroll
            for (int e = 0; e < 4; ++e)
                *(v2s*)&s_stage[((lane << 2) + e) * 40 + j0] =
                    (v2s){(short)f2bf(a0[e]), (short)f2bf(a1[e])};
        }
        __syncthreads();
        v8s ah  = *(const v8s*)&s_stage[((wv << 4) + nn) * 40 + (quad << 3)];
        v8s beh = *(const v8s*)&s_eh[nn * 136 + (jc << 5) + (quad << 3)];
        v8s bel = *(const v8s*)&s_el[nn * 136 + (jc << 5) + (quad << 3)];
        tacc = __builtin_amdgcn_mfma_f32_16x16x32_bf16(ah, beh, tacc, 0, 0, 0);
        tacc = __builtin_amdgcn_mfma_f32_16x16x32_bf16(ah, bel, tacc, 0, 0, 0);
    }

    // outputs: tpart[p][bg][i][k]
    #pragma unroll
    for (int r = 0; r < 4; ++r) {
        int k = (wv << 4) + (quad << 2) + r;
        tpart_out[(((p << 6) + bg) << 12) + (nn << 8) + k] = tacc[r];
    }
    __syncthreads();
    if (tid < 16) {
        float ss = 0.f;
        #pragma unroll
        for (int w = 0; w < 8; ++w) ss += s_sefp[(w << 4) + tid];
        sefpart_out[(((p << 6) + bg) << 4) + tid] = ss;
    }
}

// ---------------------------------------------------------------------------
extern "C" void kernel_launch(void* const* d_in, const int* in_sizes, int n_in,
                              void* d_out, int out_size, void* d_ws, size_t ws_size,
                              hipStream_t stream) {
    const float* U = (const float*)d_in[0];   // [32,1024,256]
    const float* W = (const float*)d_in[1];   // [256,2048]
    float* out = (float*)d_out;               // [32,32,64]
    float* ws = (float*)d_ws;

    // ws (float slots): total ~6.14M = 24.5 MB
    float* t0p   = ws;                  // [32][16][256]      = 131,072
    float* WT    = t0p + 131072;        // [2048][256]        = 524,288
    float* bmatg = WT + 524288;         // [64][1024][16]     = 1,048,576
    float* tpA   = bmatg + 1048576;     // [8][64][16][256]   = 2,097,152
    float* tpB   = tpA + 2097152;       // [8][64][16][256]   = 2,097,152
    float* sefA  = tpB + 2097152;       // [8][64][16]        = 8,192
    float* sefB  = sefA + 8192;         // [8][64][16]        = 8,192
    short* wbt_h = (short*)(sefB + 8192);   // [64][16][256] shorts
    short* wbt_l = wbt_h + 262144;

    k_init<<<640, 256, 0, stream>>>(U, W, t0p, WT);
    k_sv<<<1024, 256, 0, stream>>>(t0p, nullptr, nullptr, W, WT,
                                   wbt_h, wbt_l, out, 0, 0);
    k_pass<<<512, 1024, 0, stream>>>(U, wbt_h, wbt_l, bmatg, tpA, sefA, 0);
    k_sv<<<1024, 256, 0, stream>>>(t0p, tpA, sefA, W, WT,
                                   wbt_h, wbt_l, out, 1, 0);
    k_pass<<<512, 1024, 0, stream>>>(U, wbt_h, wbt_l, bmatg, tpB, sefB, 1);
    k_sv<<<1024, 256, 0, stream>>>(t0p, tpB, sefB, W, WT,
                                   wbt_h, wbt_l, out, 1, 1);
}

// Round 9
// 131.415 us; speedup vs baseline: 1.8566x; 1.0782x over previous
//
#include <hip/hip_runtime.h>
#include <math.h>

// Capsule routing B=32, N=1024(j), D=256(k), NC=32(i), DC=64(d). Factored
// (no u_hat), MFMA 16x16x32 bf16:
//   delta[j,i] = U[b,j,:].w[:,i]    (k_pass phase D: A=U row-major, B=w hi/lo)
//   e = exp(logit), sef = sum_j e   (fp32 on reduced C-frags)
//   t[i,k] = sum_j e[i,j] U[j,k]    (k_pass phase T: A=e hi/lo, B=U fragments
//                                    read DIRECTLY from the row-major U tile)
//   s = tW_i; v = s*rsqrt(||s||^2+eps*sef^2); w = W_i v   (k_sv, fp32)
// Round-9: 64-j slices staged ONCE per pass (U read 1x not 2x, 3 barriers not
// 26, ~16 f2bf/thread not ~56). Delta K split 4-way across waves + LDS reduce.
// 77.3 KB LDS -> 2 blocks/CU. 6 plain launches, no atomics, no grid.sync.

typedef short v8s __attribute__((ext_vector_type(8)));
typedef short v4s __attribute__((ext_vector_type(4)));
typedef float v4f __attribute__((ext_vector_type(4)));

__device__ __forceinline__ unsigned short f2bf(float x) {
    unsigned u = __float_as_uint(x);
    u = u + 0x7fffu + ((u >> 16) & 1u);
    return (unsigned short)(u >> 16);
}
__device__ __forceinline__ float bf2f(unsigned short h) {
    return __uint_as_float(((unsigned)h) << 16);
}

// ---------------------------------------------------------------------------
// k_init: bid<512: colsum partials t0p[b][q][k] (iter-0 uniform softmax);
//         bid>=512: transpose W (256x2048) -> WT (2048x256), 64x64 tiles.
__global__ __launch_bounds__(256) void k_init(const float* __restrict__ U,
                                              const float* __restrict__ W,
                                              float* __restrict__ t0p,
                                              float* __restrict__ WT) {
    int bid = blockIdx.x, tid = threadIdx.x;
    if (bid < 512) {
        int b = bid >> 4, q = bid & 15;
        const float* Up = U + (((b << 10) + (q << 6)) << 8) + tid;
        float acc = 0.f;
        #pragma unroll 16
        for (int jl = 0; jl < 64; ++jl) acc += Up[jl << 8];
        t0p[(b << 12) + (q << 8) + tid] = acc * (1.0f / 1024.0f);
    } else {
        __shared__ float tile[64 * 65];
        int tix = bid - 512;                 // 0..127
        int k0 = (tix >> 5) << 6, c0 = (tix & 31) << 6;
        int cc = tid & 63, g4 = tid >> 6;
        #pragma unroll
        for (int r = 0; r < 16; ++r) {
            int kk = (g4 << 4) + r;
            tile[kk * 65 + cc] = W[(k0 + kk) * 2048 + c0 + cc];
        }
        __syncthreads();
        int kk = tid & 63;
        #pragma unroll
        for (int r = 0; r < 16; ++r) {
            int c = (g4 << 4) + r;
            WT[(c0 + c) * 256 + k0 + kk] = tile[kk * 65 + c];
        }
    }
}

// ---------------------------------------------------------------------------
// k_sv: per (b,iG): t[k] = sum of 16 partials; s = tW_i; v = squash(.,sef);
// w = W_i v -> wbt hi/lo (bf16). grid 1024, block 256.
__global__ __launch_bounds__(256) void k_sv(const float* __restrict__ t0p,
                                            const float* __restrict__ tpart,
                                            const float* __restrict__ sefpart,
                                            const float* __restrict__ W,
                                            const float* __restrict__ WT,
                                            short* __restrict__ wbt_h,
                                            short* __restrict__ wbt_l,
                                            float* __restrict__ out,
                                            int mode, int writeOut) {
    __shared__ float t_lds[256];
    __shared__ float spart[256];
    __shared__ __align__(16) float v_lds[64];
    __shared__ __align__(16) v4f spartw[256];
    __shared__ float sefv_s;
    int bid = blockIdx.x, tid = threadIdx.x;
    int b = bid >> 5, iG = bid & 31;
    int bg = (b << 1) | (iG >> 4), il = iG & 15;

    float acc = 0.f;
    if (mode == 0) {
        const float* tb = t0p + (b << 12) + tid;
        #pragma unroll
        for (int q = 0; q < 16; ++q) acc += tb[q << 8];
        if (tid == 0) sefv_s = 1.0f;
    } else {
        const float* tb = tpart + (((bg << 4) + il) << 8) + tid;
        #pragma unroll
        for (int p = 0; p < 16; ++p) acc += tb[p << 18];  // stride 64*16*256
        if (tid == 0) {
            float s = 0.f;
            #pragma unroll
            for (int p = 0; p < 16; ++p) s += sefpart[(p << 10) + (bg << 4) + il];
            sefv_s = s;
        }
    }
    t_lds[tid] = acc;
    __syncthreads();

    // s-phase: (d = tid&63, kq = tid>>6), coalesced 256B W reads
    int d = tid & 63, kq = tid >> 6;
    const float* Wc = W + ((kq << 6) * 2048) + (iG << 6) + d;
    float s = 0.f;
    #pragma unroll 4
    for (int kk = 0; kk < 64; ++kk)
        s += t_lds[(kq << 6) + kk] * Wc[kk * 2048];
    spart[tid] = s;
    __syncthreads();

    if (tid < 64) {
        float sv = spart[tid] + spart[tid + 64] + spart[tid + 128] + spart[tid + 192];
        float n2 = sv * sv;
        #pragma unroll
        for (int m = 1; m < 64; m <<= 1) n2 += __shfl_xor(n2, m, 64);
        float sf = sefv_s;
        float v = sv * rsqrtf(n2 + 1e-7f * sf * sf);
        v_lds[tid] = v;
        if (writeOut) out[(bid << 6) + tid] = v;
    }
    __syncthreads();
    if (writeOut) return;

    // w-phase: (k4 = tid&63, dq = tid>>6), WT gives coalesced 1KB/instr reads
    int k4 = tid & 63, dq = tid >> 6;
    const float4* WT4 = (const float4*)WT;
    v4f wp = {0.f, 0.f, 0.f, 0.f};
    #pragma unroll
    for (int dd = 0; dd < 16; ++dd) {
        float vv = v_lds[(dq << 4) + dd];
        float4 wt = WT4[((iG << 6) + (dq << 4) + dd) * 64 + k4];
        wp.x += vv * wt.x; wp.y += vv * wt.y; wp.z += vv * wt.z; wp.w += vv * wt.w;
    }
    spartw[(dq << 6) + k4] = wp;
    __syncthreads();
    if (tid < 64) {
        v4f w = spartw[tid] + spartw[64 + tid] + spartw[128 + tid] + spartw[192 + tid];
        float wv4[4] = {w.x, w.y, w.z, w.w};
        unsigned short wh[4], wl[4];
        #pragma unroll
        for (int e = 0; e < 4; ++e) {
            wh[e] = f2bf(wv4[e]);
            wl[e] = f2bf(wv4[e] - bf2f(wh[e]));
        }
        int base = (((bg << 4) + il) << 8) + (tid << 2);
        *(v4s*)&wbt_h[base] = (v4s){(short)wh[0], (short)wh[1], (short)wh[2], (short)wh[3]};
        *(v4s*)&wbt_l[base] = (v4s){(short)wl[0], (short)wl[1], (short)wl[2], (short)wl[3]};
    }
}

// ---------------------------------------------------------------------------
// k_pass v3: block = (b, p = 64-j slice, g2 = 16-capsule group), grid 1024x1024.
// Stage U[64j][256k] bf16 ONCE; phase D (delta) splits K 4-ways over 16 waves
// (4 j-tiles x 4 K-quarters) + LDS reduce; phase T reads U B-fragments directly
// from the row-major tile (8x ds_read_u16). 3 barriers total.
__global__ __launch_bounds__(1024, 8) void k_pass(const float* __restrict__ U,
                                                  const short* __restrict__ wbt_h,
                                                  const short* __restrict__ wbt_l,
                                                  float* __restrict__ bmatg,
                                                  float* __restrict__ tpart_out,
                                                  float* __restrict__ sefpart_out,
                                                  int addold) {
    __shared__ short s_U[64 * 268];      // 34,304 B [j][k] pad 12 (bank-spread)
    __shared__ short s_wh[16 * 264];     // 8,448
    __shared__ short s_wl[16 * 264];     // 8,448
    __shared__ short s_eh[16 * 72];      // 2,304  [i][j] pad 8
    __shared__ short s_el[16 * 72];      // 2,304
    __shared__ float s_red[16 * 320];    // 20,480 [kq*4+mt][rr*20+nn] (2-way banks)
    __shared__ float s_sefp[16 * 16];    // 1,024            total 77,312 B

    const int tid = threadIdx.x, wv = tid >> 6, lane = tid & 63;
    const int quad = lane >> 4, nn = lane & 15;
    const int blk = blockIdx.x;
    const int b = blk & 31, pg = blk >> 5;   // same-b blocks share XCD
    const int p = pg >> 1, g2 = pg & 1;
    const int bg = (b << 1) | g2;
    const int rowbase = (b << 10) + (p << 6);
    const float4* U4 = (const float4*)U;

    // reduce-phase lane mapping (also used for the bold prefetch)
    const int mt2 = wv & 3, jq = wv >> 2;
    const int rr = (jq << 2) + quad;
    const int jloc = (mt2 << 4) + rr;
    const int ga = (((bg << 10) + (p << 6) + jloc) << 4) + nn;  // bmat [bg][j][i]
    float bold = 0.f;
    if (addold) bold = bmatg[ga];

    // stage w hi/lo (waves 0-7)
    if (tid < 512) {
        int row = tid >> 5, seg = tid & 31;
        int gidx = (((bg << 4) + row) << 8) + (seg << 3);
        *(v8s*)&s_wh[row * 264 + (seg << 3)] = *(const v8s*)(wbt_h + gidx);
        *(v8s*)&s_wl[row * 264 + (seg << 3)] = *(const v8s*)(wbt_l + gidx);
    }
    // stage U once: 4 sweeps of 16 rows x 64 f4 (all loads in flight)
    {
        int col = tid & 63, row0 = tid >> 6;
        float4 g[4];
        #pragma unroll
        for (int q = 0; q < 4; ++q)
            g[q] = U4[(rowbase + row0 + (q << 4)) * 64 + col];
        #pragma unroll
        for (int q = 0; q < 4; ++q)
            *(v4s*)&s_U[(row0 + (q << 4)) * 268 + (col << 2)] =
                (v4s){(short)f2bf(g[q].x), (short)f2bf(g[q].y),
                      (short)f2bf(g[q].z), (short)f2bf(g[q].w)};
    }
    __syncthreads();

    // ---- phase D: delta partials, wave = (mt = j-tile, kq = K-quarter) ----
    {
        const int mt = wv & 3, kq = wv >> 2;
        v4f dacc = {0.f, 0.f, 0.f, 0.f};
        #pragma unroll
        for (int c = 0; c < 2; ++c) {
            int kb = (kq << 6) + (c << 5) + (quad << 3);
            v8s a  = *(const v8s*)&s_U[((mt << 4) + nn) * 268 + kb];
            v8s bh = *(const v8s*)&s_wh[nn * 264 + kb];
            v8s bl = *(const v8s*)&s_wl[nn * 264 + kb];
            dacc = __builtin_amdgcn_mfma_f32_16x16x32_bf16(a, bh, dacc, 0, 0, 0);
            dacc = __builtin_amdgcn_mfma_f32_16x16x32_bf16(a, bl, dacc, 0, 0, 0);
        }
        #pragma unroll
        for (int r = 0; r < 4; ++r)
            s_red[wv * 320 + ((quad << 2) + r) * 20 + nn] = dacc[r];
    }
    __syncthreads();

    // ---- K-reduce + logits + exp + e hi/lo + sef partials ----
    {
        float val = bold;
        #pragma unroll
        for (int kq = 0; kq < 4; ++kq)
            val += s_red[((kq << 2) + mt2) * 320 + rr * 20 + nn];
        if (!addold) bmatg[ga] = val;
        float e = __expf(val);
        unsigned short eh = f2bf(e);
        s_eh[nn * 72 + jloc] = (short)eh;
        s_el[nn * 72 + jloc] = (short)f2bf(e - bf2f(eh));
        float se = e;
        se += __shfl_xor(se, 16, 64);
        se += __shfl_xor(se, 32, 64);
        if (lane < 16) s_sefp[(wv << 4) + lane] = se;
    }
    __syncthreads();

    // ---- phase T: wave = 16-k N-tile; A = e hi/lo, B = U direct fragments ----
    {
        v4f tacc = {0.f, 0.f, 0.f, 0.f};
        const int k0 = wv << 4;
        #pragma unroll
        for (int jc = 0; jc < 2; ++jc) {
            v8s aeh = *(const v8s*)&s_eh[nn * 72 + (jc << 5) + (quad << 3)];
            v8s ael = *(const v8s*)&s_el[nn * 72 + (jc << 5) + (quad << 3)];
            short bu[8];
            #pragma unroll
            for (int jj = 0; jj < 8; ++jj)
                bu[jj] = s_U[((jc << 5) + (quad << 3) + jj) * 268 + k0 + nn];
            v8s bf = (v8s){bu[0], bu[1], bu[2], bu[3], bu[4], bu[5], bu[6], bu[7]};
            tacc = __builtin_amdgcn_mfma_f32_16x16x32_bf16(aeh, bf, tacc, 0, 0, 0);
            tacc = __builtin_amdgcn_mfma_f32_16x16x32_bf16(ael, bf, tacc, 0, 0, 0);
        }
        // D: row = i = quad*4+r, col = k-local = nn
        #pragma unroll
        for (int r = 0; r < 4; ++r) {
            int i = (quad << 2) + r;
            tpart_out[(((((p << 6) + bg) << 4) + i) << 8) + k0 + nn] = tacc[r];
        }
    }
    if (tid < 16) {
        float ss = 0.f;
        #pragma unroll
        for (int w = 0; w < 16; ++w) ss += s_sefp[(w << 4) + tid];
        sefpart_out[(p << 10) + (bg << 4) + tid] = ss;
    }
}

// ---------------------------------------------------------------------------
extern "C" void kernel_launch(void* const* d_in, const int* in_sizes, int n_in,
                              void* d_out, int out_size, void* d_ws, size_t ws_size,
                              hipStream_t stream) {
    const float* U = (const float*)d_in[0];   // [32,1024,256]
    const float* W = (const float*)d_in[1];   // [256,2048]
    float* out = (float*)d_out;               // [32,32,64]
    float* ws = (float*)d_ws;

    // ws (float slots): total ~6.0M = 24 MB
    float* t0p   = ws;                  // [32][16][256]      = 131,072
    float* WT    = t0p + 131072;        // [2048][256]        = 524,288
    float* bmatg = WT + 524288;         // [64][1024][16]     = 1,048,576
    float* tp    = bmatg + 1048576;     // [16][64][16][256]  = 4,194,304
    float* sef   = tp + 4194304;        // [16][64][16]       = 16,384
    short* wbt_h = (short*)(sef + 16384);   // [64][16][256] shorts
    short* wbt_l = wbt_h + 262144;

    k_init<<<640, 256, 0, stream>>>(U, W, t0p, WT);
    k_sv<<<1024, 256, 0, stream>>>(t0p, nullptr, nullptr, W, WT,
                                   wbt_h, wbt_l, out, 0, 0);
    k_pass<<<1024, 1024, 0, stream>>>(U, wbt_h, wbt_l, bmatg, tp, sef, 0);
    k_sv<<<1024, 256, 0, stream>>>(t0p, tp, sef, W, WT,
                                   wbt_h, wbt_l, out, 1, 0);
    k_pass<<<1024, 1024, 0, stream>>>(U, wbt_h, wbt_l, bmatg, tp, sef, 1);
    k_sv<<<1024, 256, 0, stream>>>(t0p, tp, sef, W, WT,
                                   wbt_h, wbt_l, out, 1, 1);
}